// Round 19
// baseline (212.555 us; speedup 1.0000x reference)
//
#include <hip/hip_runtime.h>

typedef int v4i __attribute__((ext_vector_type(4)));

constexpr int Kdim = 4096;
constexpr int Ndim = 4096;
constexpr int MtotC = 8192;
constexpr int BM = 256;
constexpr int BN = 256;

#define AS1 __attribute__((address_space(1)))
#define AS3 __attribute__((address_space(3)))

// ---------------- pack: x int32->int8 linear; W int32->int8 TRANSPOSED frag stream ----
// w8t layout: [strip=n>>6][u=k16>>3][h][g][lane=fsl*16+frow][16B]; strip=64 cols.
__global__ void pack_both(const int* __restrict__ xq, const int* __restrict__ wq,
                          signed char* __restrict__ x8, signed char* __restrict__ w8t) {
    const size_t gid = (size_t)blockIdx.x * blockDim.x + threadIdx.x;
    if (blockIdx.x < 2048) {
        // x: 8Mi char4 granules over 524288 threads
        const size_t nx4 = (size_t)MtotC * Kdim / 4;
        for (size_t j = gid; j < nx4; j += 524288) {
            const int4 v = ((const int4*)xq)[j];
            char4 c;
            c.x = (signed char)v.x; c.y = (signed char)v.y;
            c.z = (signed char)v.z; c.w = (signed char)v.w;
            ((char4*)x8)[j] = c;
        }
    } else {
        // W: 1Mi 16B-granules over 131072 threads; read 64B contiguous, write scattered
        const size_t t2 = gid - (size_t)2048 * 256;
        const size_t ng = (size_t)Ndim * (Kdim / 16);   // 1Mi
        for (size_t ggg = t2; ggg < ng; ggg += 131072) {
            const int n   = (int)(ggg >> 8);            // col (output channel)
            const int k16 = (int)(ggg & 255);
            const int* src = wq + (size_t)n * Kdim + k16 * 16;
            char4 c[4];
#pragma unroll
            for (int q = 0; q < 4; ++q) {
                const int4 v = ((const int4*)src)[q];
                c[q].x = (signed char)v.x; c[q].y = (signed char)v.y;
                c[q].z = (signed char)v.z; c[q].w = (signed char)v.w;
            }
            const int strip = n >> 6, cw = n & 63;
            const int g = cw >> 4, frow = cw & 15;
            const int u = k16 >> 3, h = (k16 >> 2) & 1, fsl = k16 & 3;
            const int lane = fsl * 16 + frow;
            char4* dst = (char4*)(w8t + (size_t)strip * 262144 + u * 8192 + h * 4096
                                  + g * 1024 + lane * 16);
#pragma unroll
            for (int q = 0; q < 4; ++q) dst[q] = c[q];
        }
    }
}

// ---------------- int8 GEMM, 256x256: A via LDS (64KB, 4 regions), B global->reg ----------------
// Phase m (64B K-half): VMC(2) [drains B(m)+A(m+1), leaves A(m+2)]; BAR;
// issue B(m+1)[4 coalesced 1KB loads] then stage A(m+3)[2 gload_lds];
// ds_read A half m+1 -> spare set; LGKM8 (drains previous set); 32 MFMA on
// current A-set x B-set(m%2). B never touches LDS (wave-private cols).
// A swizzle: slot' = slot ^ ((row>>1)&3) (verified 0-conflict).
__global__ __launch_bounds__(512, 2) void i8gemm_kernel(
    const signed char* __restrict__ A,
    const signed char* __restrict__ Bt,   // transposed frag stream
    const float* __restrict__ sx,
    const float* __restrict__ wsc,
    const float* __restrict__ bias,
    float* __restrict__ C)
{
    __shared__ signed char smem[65536];   // 4 regions x 16KB (A only)

    const int tid  = threadIdx.x;
    const int wave = tid >> 6;
    const int lane = tid & 63;
    const int wr = wave >> 2;     // 0..1  (128-row strip)
    const int wc = wave & 3;      // 0..3  (64-col strip, wave-private B)

    // XCD-aware swizzle: 8 regions of 8bm x 8bn
    const int xr_ = blockIdx.x & 7;
    const int idx = blockIdx.x >> 3;
    const int bm = ((xr_ & 3) * 8 + (idx & 7)) * BM;
    const int bn = ((xr_ >> 2) * 8 + (idx >> 3)) * BN;

    // ---- A staging constants (2 gload_lds per thread per half) ----
    const int srow  = tid >> 2;                             // 0..127
    const int gslot = (tid & 3) ^ ((srow >> 1) & 3);        // pre-inverse-swizzled 16B slot
    const signed char* Ag = A + (size_t)(bm + srow) * Kdim + gslot * 16;
    const int sdst = srow * 64 + (tid & 3) * 16;            // linear lane-contiguous dest

    // ---- A fragment read constants ----
    const int frow = lane & 15;
    const int fsl  = lane >> 4;
    const int rsw  = ((fsl ^ ((frow >> 1) & 3)) << 4);
    const int aro  = (wr * 128 + frow) * 64 + rsw;          // + f*1024 (+ region base)

    // ---- B stream base (wave-private strip) ----
    const signed char* Bw = Bt + ((size_t)(bn >> 6) + wc) * 262144 + lane * 16;

    v4i acc[8][4];
#pragma unroll
    for (int f = 0; f < 8; ++f)
#pragma unroll
        for (int g = 0; g < 4; ++g)
#pragma unroll
            for (int e = 0; e < 4; ++e) acc[f][g][e] = 0;

    v4i avA[8], avB[8], bv0[4], bv1[4];   // static ping-pong sets (rule #20)

#define REG_OF(M) (((M) & 3) * 16384)

#define STG_A(M) do {                                                                  \
    signed char* dst = smem + REG_OF(M) + sdst;                                        \
    const signed char* sa = Ag + (size_t)(M) * 64;                                     \
    __builtin_amdgcn_global_load_lds((const AS1 void*)sa,                        (AS3 void*)dst,          16, 0, 0); \
    __builtin_amdgcn_global_load_lds((const AS1 void*)(sa + (size_t)128 * Kdim), (AS3 void*)(dst + 8192), 16, 0, 0); \
} while (0)

#define B_LOAD(BV, M) do {                                                             \
    const signed char* bsrc = Bw + (size_t)((M) >> 1) * 8192 + ((M) & 1) * 4096;       \
    _Pragma("unroll") for (int g_ = 0; g_ < 4; ++g_)                                   \
        BV[g_] = *(const v4i*)(bsrc + g_ * 1024);                                      \
} while (0)

#define READ_A(AV, M) do {                                                             \
    const signed char* base_ = smem + REG_OF(M);                                       \
    _Pragma("unroll") for (int f_ = 0; f_ < 8; ++f_)                                   \
        AV[f_] = *(const v4i*)(base_ + aro + f_ * 1024);                               \
} while (0)

#define MFMA_HALF(AV, BV) do {                                                         \
    __builtin_amdgcn_s_setprio(1);                                                     \
    _Pragma("unroll") for (int f_ = 0; f_ < 8; ++f_)                                   \
    _Pragma("unroll") for (int g_ = 0; g_ < 4; ++g_)                                   \
        acc[f_][g_] = __builtin_amdgcn_mfma_i32_16x16x64_i8(AV[f_], BV[g_], acc[f_][g_], 0, 0, 0); \
    __builtin_amdgcn_s_setprio(0);                                                     \
} while (0)

#define BAR    __builtin_amdgcn_s_barrier()
#define LGKM8  do { asm volatile("s_waitcnt lgkmcnt(8)" ::: "memory");                 \
                    __builtin_amdgcn_sched_barrier(0); } while (0)
#define LGKM0  do { asm volatile("s_waitcnt lgkmcnt(0)" ::: "memory");                 \
                    __builtin_amdgcn_sched_barrier(0); } while (0)
#define VMC(N) asm volatile("s_waitcnt vmcnt(" #N ")" ::: "memory")

    // ---- prologue: FIFO = A0(2), A1(2), B0(4), A2(2); drain A0; read half 0 ----
    STG_A(0);
    STG_A(1);
    B_LOAD(bv0, 0);
    STG_A(2);
    VMC(8);                 // drain A0 (leaves A1, B0, A2)
    BAR;
    READ_A(avA, 0);

    // ---- steady: phases m = 0..60 (paired; even uses avA/bv0, odd avB/bv1) ----
    // entry invariant: outstanding FIFO = [A(m+1):2, B(m):4, A(m+2):2]
    for (int u = 0; u < 30; ++u) {
        const int m = 2 * u;
        // phase m (even)
        VMC(2); BAR;
        B_LOAD(bv1, m + 1);
        STG_A(m + 3);
        READ_A(avB, m + 1);
        LGKM8;
        MFMA_HALF(avA, bv0);
        // phase m+1 (odd)
        VMC(2); BAR;
        B_LOAD(bv0, m + 2);
        STG_A(m + 4);
        READ_A(avA, m + 2);
        LGKM8;
        MFMA_HALF(avB, bv1);
    }
    // phase 60
    VMC(2); BAR;
    B_LOAD(bv1, 61);
    STG_A(63);
    READ_A(avB, 61);
    LGKM8;
    MFMA_HALF(avA, bv0);
    // phase 61 (no more staging): entry FIFO = [A62:2, B61:4, A63:2]
    VMC(2); BAR;
    B_LOAD(bv0, 62);
    READ_A(avA, 62);
    LGKM8;
    MFMA_HALF(avB, bv1);
    // phase 62: entry FIFO = [A63:2, B62:4]
    VMC(0); BAR;
    B_LOAD(bv1, 63);
    READ_A(avB, 63);
    LGKM8;
    MFMA_HALF(avA, bv0);
    // phase 63
    VMC(0);
    LGKM0;
    MFMA_HALF(avB, bv1);

    // ---- epilogue: dequant + bias, fp32 store ----
    // 16x16 C/D map: col = lane&15, row = (lane>>4)*4 + reg
    const int orow0 = bm + wr * 128;
    const int ocol0 = bn + wc * 64;
    float wsv[4], bvv[4];
#pragma unroll
    for (int g = 0; g < 4; ++g) {
        const int col = ocol0 + g * 16 + frow;
        wsv[g] = wsc[col];
        bvv[g] = bias[col];
    }
#pragma unroll
    for (int f = 0; f < 8; ++f) {
#pragma unroll
        for (int jr = 0; jr < 4; ++jr) {
            const int row = orow0 + f * 16 + fsl * 4 + jr;
            const float s = sx[row];
#pragma unroll
            for (int g = 0; g < 4; ++g) {
                const int col = ocol0 + g * 16 + frow;
                C[(size_t)row * Ndim + col] = (float)acc[f][g][jr] * s * wsv[g] + bvv[g];
            }
        }
    }
#undef REG_OF
#undef STG_A
#undef B_LOAD
#undef READ_A
#undef MFMA_HALF
#undef BAR
#undef LGKM8
#undef LGKM0
#undef VMC
}

extern "C" void kernel_launch(void* const* d_in, const int* in_sizes, int n_in,
                              void* d_out, int out_size, void* d_ws, size_t ws_size,
                              hipStream_t stream) {
    (void)in_sizes; (void)n_in; (void)out_size; (void)ws_size;
    const int*   x_q  = (const int*)d_in[0];
    const float* sx   = (const float*)d_in[1];
    const int*   w_q  = (const int*)d_in[2];
    const float* wsc  = (const float*)d_in[3];
    const float* bias = (const float*)d_in[4];
    float* out = (float*)d_out;

    signed char* x8  = (signed char*)d_ws;
    signed char* w8t = x8 + (size_t)MtotC * Kdim;

    pack_both<<<2560, 256, 0, stream>>>(x_q, w_q, x8, w8t);

    const int nwg = (MtotC / BM) * (Ndim / BN);  // 512
    i8gemm_kernel<<<nwg, 512, 0, stream>>>(x8, w8t, sx, wsc, bias, out);
}